// Round 6
// baseline (155.447 us; speedup 1.0000x reference)
//
#include <hip/hip_runtime.h>

#define H_SIZE 1024
#define N_HEADS 16
#define D_K 64
#define SEQ 2048
#define BATCH 2
#define M_TOT 4096  // BATCH*SEQ

typedef __bf16 __attribute__((ext_vector_type(8))) bf16_8;
typedef float __attribute__((ext_vector_type(4))) f32x4;
typedef float __attribute__((ext_vector_type(16))) f32x16;
typedef int __attribute__((ext_vector_type(4))) int4v;

// row-swizzle for 128B-row LDS tiles: spread rows sharing (r&7) across segments
#define SWZ(r) ((((r) & 7) ^ (((r) >> 3) & 7)))

__device__ __forceinline__ ushort f2bf(float f) {
    unsigned int u = __float_as_uint(f);
    unsigned int r = (u + 0x7FFFu + ((u >> 16) & 1u)) >> 16;
    return (ushort)r;
}

__device__ __forceinline__ unsigned int cvtpk(float lo, float hi) {
    unsigned int r;
    asm("v_cvt_pk_bf16_f32 %0, %1, %2" : "=v"(r) : "v"(lo), "v"(hi));
    return r;
}

__device__ __forceinline__ float exp2_raw(float x) {
    float r;
    asm("v_exp_f32 %0, %1" : "=v"(r) : "v"(x));
    return r;
}

__device__ __forceinline__ void gld16(void* lds, const void* g) {
    __builtin_amdgcn_global_load_lds(
        (const __attribute__((address_space(1))) unsigned int*)g,
        (__attribute__((address_space(3))) unsigned int*)lds, 16, 0, 0);
}

// ---------------- fused cast fp32 -> bf16 for x + 4 weight matrices ----------------
__global__ __launch_bounds__(256) void cast_all_kernel(
    const float* __restrict__ x, const float* __restrict__ wq, const float* __restrict__ wk,
    const float* __restrict__ wv, const float* __restrict__ wo,
    ushort* __restrict__ xb, ushort* __restrict__ wqb, ushort* __restrict__ wkb,
    ushort* __restrict__ wvb, ushort* __restrict__ wob) {
    int i = blockIdx.x * 256 + threadIdx.x;  // float4 index
    const float* src;
    ushort* dst;
    int off;
    if (i < 1048576) {          // x: 4096*1024/4
        src = x; dst = xb; off = i;
    } else {
        int j = i - 1048576;    // each W: 1024*1024/4 = 262144
        int w = j >> 18;
        off = j & 262143;
        src = (w == 0) ? wq : (w == 1) ? wk : (w == 2) ? wv : wo;
        dst = (w == 0) ? wqb : (w == 1) ? wkb : (w == 2) ? wvb : wob;
    }
    float4 v = ((const float4*)src)[off];
    ushort4 o;
    o.x = f2bf(v.x); o.y = f2bf(v.y); o.z = f2bf(v.z); o.w = f2bf(v.w);
    ((ushort4*)dst)[off] = o;
}

// ---------------- fused QKV GEMM, gld16-direct 2-phase, BK=64 (m97 structure) ----------------
// grid (M/128, 24): blockIdx.y>>3 selects {Q,K,V}.
//   Q -> bf16 [b,h,l,dk] scaled 0.125*log2e (exp2 softmax);
//   K -> [b,h,l,dk] SWZ-swizzled;  V -> [b,h,dk,l] transposed, SWZ-swizzled.
__global__ __launch_bounds__(256) void gemm_qkv(
    const ushort* __restrict__ A, const ushort* __restrict__ wq,
    const ushort* __restrict__ wk, const ushort* __restrict__ wv,
    const float* __restrict__ bq, const float* __restrict__ bk, const float* __restrict__ bv,
    ushort* __restrict__ Qb, ushort* __restrict__ Kb, ushort* __restrict__ Vtb) {
    __shared__ ushort As[2][128 * 64];
    __shared__ ushort Bs[2][128 * 64];
    const int tid = threadIdx.x;
    const int lane = tid & 63, wid = tid >> 6;
    const int wr = wid >> 1, wc = wid & 1;
    const int hi = lane >> 4, lo = lane & 15;
    const int bm0 = blockIdx.x * 128;
    const int t3 = blockIdx.y >> 3;
    const int bn0 = (blockIdx.y & 7) * 128;
    const ushort* Bw = (t3 == 0) ? wq : (t3 == 1) ? wk : wv;
    const float* bias = (t3 == 0) ? bq : (t3 == 1) ? bk : bv;

    f32x4 acc[4][4] = {};

    // staging: thread t, chunk c -> LDS byte (c*256+t)*16 == row (c*32 + t>>3), seg (t&7)
    const int srow = tid >> 3;
    const int sseg = (tid & 7) * 8;  // ushort offset
    const ushort* gaB = A + (size_t)(bm0 + srow) * H_SIZE + sseg;
    const ushort* gbB = Bw + (size_t)(bn0 + srow) * H_SIZE + sseg;
    const int ldsOff = tid * 16;  // bytes

#define STAGE(bb, kt)                                                     \
    {                                                                     \
        char* la = (char*)&As[bb][0] + ldsOff;                            \
        char* lb = (char*)&Bs[bb][0] + ldsOff;                            \
        gld16(la, gaB + (kt));                                            \
        gld16(la + 4096, gaB + 32 * H_SIZE + (kt));                       \
        gld16(la + 8192, gaB + 64 * H_SIZE + (kt));                       \
        gld16(la + 12288, gaB + 96 * H_SIZE + (kt));                      \
        gld16(lb, gbB + (kt));                                            \
        gld16(lb + 4096, gbB + 32 * H_SIZE + (kt));                       \
        gld16(lb + 8192, gbB + 64 * H_SIZE + (kt));                       \
        gld16(lb + 12288, gbB + 96 * H_SIZE + (kt));                      \
    }

    STAGE(0, 0);
    __syncthreads();
    int cur = 0;
    constexpr int NT = H_SIZE / 64;
    for (int t = 0; t < NT; t++) {
        if (t + 1 < NT) STAGE(cur ^ 1, (t + 1) * 64);
#pragma unroll
        for (int kk = 0; kk < 64; kk += 32) {
            bf16_8 af[4], bfv[4];
            const ushort* pa = &As[cur][(wr * 64 + lo) * 64 + kk + hi * 8];
            const ushort* pb = &Bs[cur][(wc * 64 + lo) * 64 + kk + hi * 8];
#pragma unroll
            for (int i = 0; i < 4; i++) af[i] = *(const bf16_8*)(pa + i * 16 * 64);
#pragma unroll
            for (int i = 0; i < 4; i++) bfv[i] = *(const bf16_8*)(pb + i * 16 * 64);
#pragma unroll
            for (int mi = 0; mi < 4; mi++)
#pragma unroll
                for (int ni = 0; ni < 4; ni++)
                    acc[mi][ni] = __builtin_amdgcn_mfma_f32_16x16x32_bf16(
                        af[mi], bfv[ni], acc[mi][ni], 0, 0, 0);
        }
        __syncthreads();
        cur ^= 1;
    }
#undef STAGE

#pragma unroll
    for (int mi = 0; mi < 4; mi++) {
#pragma unroll
        for (int ni = 0; ni < 4; ni++) {
            const int row0 = bm0 + wr * 64 + mi * 16 + hi * 4;
            const int col = bn0 + wc * 64 + ni * 16 + lo;
            const float bv = bias[col];
            const int h = col >> 6, dk = col & 63;
            if (t3 == 2) {
                // V^T [b,h,dk,l]: 4 consecutive l -> one ushort4 (same 8-run, SWZ on dk only)
                const int b = row0 >> 11, l0 = row0 & 2047;
                const int lsw0 = (l0 & ~63) | (((((l0 >> 3) & 7) ^ SWZ(dk)) & 7) << 3) | (l0 & 7);
                ushort4 o;
                o.x = f2bf(acc[mi][ni][0] + bv);
                o.y = f2bf(acc[mi][ni][1] + bv);
                o.z = f2bf(acc[mi][ni][2] + bv);
                o.w = f2bf(acc[mi][ni][3] + bv);
                *(ushort4*)&Vtb[((size_t)(b * N_HEADS + h) * D_K + dk) * SEQ + lsw0] = o;
            } else {
#pragma unroll
                for (int rr = 0; rr < 4; rr++) {
                    const int m = row0 + rr;
                    const int b = m >> 11, l = m & 2047;
                    float val = acc[mi][ni][rr] + bv;
                    if (t3 == 0) {
                        // fold attn scale 1/8 and log2(e) for exp2 softmax
                        Qb[((size_t)(b * N_HEADS + h) * SEQ + l) * D_K + dk] =
                            f2bf(val * 0.18033688f);
                    } else {
                        int dks = ((((dk >> 3) ^ SWZ(l & 63)) & 7) << 3) | (dk & 7);
                        Kb[((size_t)(b * N_HEADS + h) * SEQ + l) * D_K + dks] = f2bf(val);
                    }
                }
            }
        }
    }
}

// ---------------- O-projection GEMM 128x64, gld16-direct 2-phase, BK=64 ----------------
__global__ __launch_bounds__(256) void gemm_o(const ushort* __restrict__ A,
                                              const ushort* __restrict__ Bw,
                                              const float* __restrict__ bias,
                                              const float* __restrict__ resid,
                                              float* __restrict__ outp) {
    __shared__ ushort As[2][128 * 64];
    __shared__ ushort Bs[2][64 * 64];
    const int tid = threadIdx.x;
    const int lane = tid & 63, wid = tid >> 6;
    const int wr = wid >> 1, wc = wid & 1;
    const int hi = lane >> 4, lo = lane & 15;
    const int bm0 = blockIdx.x * 128, bn0 = blockIdx.y * 64;

    f32x4 acc[4][2] = {};

    const int srow = tid >> 3;
    const int sseg = (tid & 7) * 8;
    const ushort* gaB = A + (size_t)(bm0 + srow) * H_SIZE + sseg;
    const ushort* gbB = Bw + (size_t)(bn0 + srow) * H_SIZE + sseg;
    const int ldsOff = tid * 16;

#define STAGE(bb, kt)                                                     \
    {                                                                     \
        char* la = (char*)&As[bb][0] + ldsOff;                            \
        char* lb = (char*)&Bs[bb][0] + ldsOff;                            \
        gld16(la, gaB + (kt));                                            \
        gld16(la + 4096, gaB + 32 * H_SIZE + (kt));                       \
        gld16(la + 8192, gaB + 64 * H_SIZE + (kt));                       \
        gld16(la + 12288, gaB + 96 * H_SIZE + (kt));                      \
        gld16(lb, gbB + (kt));                                            \
        gld16(lb + 4096, gbB + 32 * H_SIZE + (kt));                       \
    }

    STAGE(0, 0);
    __syncthreads();
    int cur = 0;
    constexpr int NT = H_SIZE / 64;
    for (int t = 0; t < NT; t++) {
        if (t + 1 < NT) STAGE(cur ^ 1, (t + 1) * 64);
#pragma unroll
        for (int kk = 0; kk < 64; kk += 32) {
            bf16_8 af[4], bfv[2];
            const ushort* pa = &As[cur][(wr * 64 + lo) * 64 + kk + hi * 8];
            const ushort* pb = &Bs[cur][(wc * 32 + lo) * 64 + kk + hi * 8];
#pragma unroll
            for (int i = 0; i < 4; i++) af[i] = *(const bf16_8*)(pa + i * 16 * 64);
#pragma unroll
            for (int i = 0; i < 2; i++) bfv[i] = *(const bf16_8*)(pb + i * 16 * 64);
#pragma unroll
            for (int mi = 0; mi < 4; mi++)
#pragma unroll
                for (int ni = 0; ni < 2; ni++)
                    acc[mi][ni] = __builtin_amdgcn_mfma_f32_16x16x32_bf16(
                        af[mi], bfv[ni], acc[mi][ni], 0, 0, 0);
        }
        __syncthreads();
        cur ^= 1;
    }
#undef STAGE

#pragma unroll
    for (int mi = 0; mi < 4; mi++) {
#pragma unroll
        for (int ni = 0; ni < 2; ni++) {
            const int row0 = bm0 + wr * 64 + mi * 16 + hi * 4;
            const int col = bn0 + wc * 32 + ni * 16 + lo;
            const float bv = bias[col];
#pragma unroll
            for (int rr = 0; rr < 4; rr++) {
                const int m = row0 + rr;
                outp[(size_t)m * H_SIZE + col] =
                    acc[mi][ni][rr] + bv + resid[(size_t)m * H_SIZE + col];
            }
        }
    }
}

// ---------------- flash attention, 32x32 MFMA, swapped QK^T, in-register exp2 softmax ----------------
// grid: (SEQ/128, BATCH*N_HEADS), 256 threads = 4 waves x 32 q-rows each.
// Q pre-scaled 0.125*log2e; K [l][dk] and V^T [dk][l] pre-swizzled with SWZ(row).
__global__ __launch_bounds__(256) void attn_kernel(const ushort* __restrict__ Q,
                                                   const ushort* __restrict__ Ksw,
                                                   const ushort* __restrict__ Vsw,
                                                   ushort* __restrict__ Out) {
    __shared__ ushort Ks[2][64 * 64];
    __shared__ ushort Vs[2][64 * 64];
    __shared__ float lsum_lds[4][32];
    const int lane = threadIdx.x & 63, wid = threadIdx.x >> 6;
    const int h32 = lane >> 5, q32 = lane & 31;
    const int bh = blockIdx.y;
    const int q0w = blockIdx.x * 128 + wid * 32;
    const ushort* Qh = Q + (size_t)bh * SEQ * D_K;
    const ushort* Kp = Ksw + (size_t)bh * SEQ * D_K;
    const ushort* Vp = Vsw + (size_t)bh * D_K * SEQ;

    bf16_8 qf[4];
#pragma unroll
    for (int tt = 0; tt < 4; tt++)
        qf[tt] = *(const bf16_8*)(Qh + (size_t)(q0w + q32) * D_K + tt * 16 + h32 * 8);

    f32x16 oacc0 = {}, oacc1 = {};
    float ls = 0.f;

    const int koff = wid * 2048 + lane * 16;
    const int vrow = wid * 16 + (lane >> 3);
    const int vseg = (lane & 7) * 16;

#define STAGE(bb, kt)                                                             \
    {                                                                             \
        const char* kg = (const char*)(Kp + (size_t)(kt) * D_K);                  \
        char* kl = (char*)&Ks[bb][0];                                             \
        gld16(kl + koff, kg + koff);                                              \
        gld16(kl + koff + 1024, kg + koff + 1024);                                \
        char* vl = (char*)&Vs[bb][0];                                             \
        gld16(vl + vrow * 128 + vseg,                                             \
              (const char*)(Vp + (size_t)vrow * SEQ + (kt)) + vseg);              \
        gld16(vl + (vrow + 8) * 128 + vseg,                                       \
              (const char*)(Vp + (size_t)(vrow + 8) * SEQ + (kt)) + vseg);        \
    }

    STAGE(0, 0);
    __syncthreads();
    int buf = 0;
    for (int t = 0; t < SEQ / 64; t++) {
        if (t + 1 < SEQ / 64) STAGE(buf ^ 1, (t + 1) * 64);
        const ushort* kb = &Ks[buf][0];
        const ushort* vb = &Vs[buf][0];
#pragma unroll
        for (int kh = 0; kh < 2; kh++) {
            f32x16 st = {};
            const int krow = kh * 32 + q32;
#pragma unroll
            for (int tt = 0; tt < 4; tt++) {
                int sg = (2 * tt + h32) ^ SWZ(krow);
                bf16_8 kf = *(const bf16_8*)(kb + krow * 64 + sg * 8);
                st = __builtin_amdgcn_mfma_f32_32x32x16_bf16(kf, qf[tt], st, 0, 0, 0);
            }
            float p[16];
#pragma unroll
            for (int rr = 0; rr < 16; rr++) p[rr] = exp2_raw(st[rr]);
            float partial = 0.f;
#pragma unroll
            for (int rr = 0; rr < 16; rr++) partial += p[rr];
            ls += partial + __shfl_xor(partial, 32);

            union { unsigned int w[4]; bf16_8 v; } pf0, pf1;
#pragma unroll
            for (int i = 0; i < 2; i++) {
                unsigned int a = cvtpk(p[2 * i], p[2 * i + 1]);
                unsigned int b = cvtpk(p[4 + 2 * i], p[4 + 2 * i + 1]);
                asm volatile("v_permlane32_swap_b32 %0, %1" : "+v"(a), "+v"(b));
                pf0.w[i] = a; pf0.w[2 + i] = b;
                unsigned int c = cvtpk(p[8 + 2 * i], p[8 + 2 * i + 1]);
                unsigned int d = cvtpk(p[12 + 2 * i], p[12 + 2 * i + 1]);
                asm volatile("v_permlane32_swap_b32 %0, %1" : "+v"(c), "+v"(d));
                pf1.w[i] = c; pf1.w[2 + i] = d;
            }

            {
                const int vr0 = q32;
                int sg0 = (4 * kh + h32) ^ SWZ(vr0);
                int sg1 = (4 * kh + 2 + h32) ^ SWZ(vr0);
                bf16_8 vf0 = *(const bf16_8*)(vb + vr0 * 64 + sg0 * 8);
                bf16_8 vf1 = *(const bf16_8*)(vb + vr0 * 64 + sg1 * 8);
                oacc0 = __builtin_amdgcn_mfma_f32_32x32x16_bf16(pf0.v, vf0, oacc0, 0, 0, 0);
                oacc0 = __builtin_amdgcn_mfma_f32_32x32x16_bf16(pf1.v, vf1, oacc0, 0, 0, 0);
            }
            {
                const int vr1 = 32 + q32;
                int sg0 = (4 * kh + h32) ^ SWZ(vr1);
                int sg1 = (4 * kh + 2 + h32) ^ SWZ(vr1);
                bf16_8 vf0 = *(const bf16_8*)(vb + vr1 * 64 + sg0 * 8);
                bf16_8 vf1 = *(const bf16_8*)(vb + vr1 * 64 + sg1 * 8);
                oacc1 = __builtin_amdgcn_mfma_f32_32x32x16_bf16(pf0.v, vf0, oacc1, 0, 0, 0);
                oacc1 = __builtin_amdgcn_mfma_f32_32x32x16_bf16(pf1.v, vf1, oacc1, 0, 0, 0);
            }
        }
        __syncthreads();
        buf ^= 1;
    }
#undef STAGE

    if (lane < 32) lsum_lds[wid][q32] = 1.0f / ls;
    const int b = bh >> 4, h = bh & 15;
#pragma unroll
    for (int rr = 0; rr < 16; rr++) {
        const int qloc = (rr & 3) + 8 * (rr >> 2) + 4 * h32;
        const float inv = lsum_lds[wid][qloc];
        const int l = q0w + qloc;
        ushort* orow = Out + ((size_t)(b * SEQ + l)) * H_SIZE + h * 64;
        orow[q32] = f2bf(oacc0[rr] * inv);
        orow[32 + q32] = f2bf(oacc1[rr] * inv);
    }
}

// ---------------- LayerNorm in-place on d_out ----------------
__global__ __launch_bounds__(256) void ln_kernel(float* __restrict__ y,
                                                 const float* __restrict__ gamma,
                                                 const float* __restrict__ beta) {
    const int row = blockIdx.x;
    float4* p = (float4*)(y + (size_t)row * H_SIZE);
    float4 v = p[threadIdx.x];
    float s = v.x + v.y + v.z + v.w;
    float s2 = v.x * v.x + v.y * v.y + v.z * v.z + v.w * v.w;
#pragma unroll
    for (int off = 1; off < 64; off <<= 1) {
        s += __shfl_xor(s, off);
        s2 += __shfl_xor(s2, off);
    }
    __shared__ float ss[4], ss2[4];
    const int wid = threadIdx.x >> 6, lane = threadIdx.x & 63;
    if (lane == 0) { ss[wid] = s; ss2[wid] = s2; }
    __syncthreads();
    s = ss[0] + ss[1] + ss[2] + ss[3];
    s2 = ss2[0] + ss2[1] + ss2[2] + ss2[3];
    const float mean = s * (1.0f / H_SIZE);
    const float var = s2 * (1.0f / H_SIZE) - mean * mean;
    const float rstd = rsqrtf(var + 1e-5f);
    const float4 g = ((const float4*)gamma)[threadIdx.x];
    const float4 bt = ((const float4*)beta)[threadIdx.x];
    float4 o;
    o.x = (v.x - mean) * rstd * g.x + bt.x;
    o.y = (v.y - mean) * rstd * g.y + bt.y;
    o.z = (v.z - mean) * rstd * g.z + bt.z;
    o.w = (v.w - mean) * rstd * g.w + bt.w;
    p[threadIdx.x] = o;
}

extern "C" void kernel_launch(void* const* d_in, const int* in_sizes, int n_in,
                              void* d_out, int out_size, void* d_ws, size_t ws_size,
                              hipStream_t stream) {
    const float* x = (const float*)d_in[0];
    const float* Wq = (const float*)d_in[1];
    const float* bq = (const float*)d_in[2];
    const float* Wk = (const float*)d_in[3];
    const float* bk = (const float*)d_in[4];
    const float* Wv = (const float*)d_in[5];
    const float* bv = (const float*)d_in[6];
    const float* Wo = (const float*)d_in[7];
    const float* bo = (const float*)d_in[8];
    const float* gamma = (const float*)d_in[9];
    const float* beta = (const float*)d_in[10];

    char* ws = (char*)d_ws;
    ushort* xb  = (ushort*)(ws);                    // 8 MB: x bf16 [4096,1024]
    ushort* wqb = (ushort*)(ws + (8u << 20));       // 2 MB each
    ushort* wkb = (ushort*)(ws + (10u << 20));
    ushort* wvb = (ushort*)(ws + (12u << 20));
    ushort* wob = (ushort*)(ws + (14u << 20));
    ushort* Qb  = (ushort*)(ws + (16u << 20));      // 8 MB [b,h,l,dk] (x 0.125*log2e)
    ushort* Kb  = (ushort*)(ws + (24u << 20));      // 8 MB [b,h,l,dk] SWZ-swizzled
    ushort* Vtb = (ushort*)(ws + (32u << 20));      // 8 MB [b,h,dk,l] SWZ-swizzled
    ushort* Ao  = (ushort*)(ws + (40u << 20));      // 8 MB attn out bf16 [m,H]

    cast_all_kernel<<<8192, 256, 0, stream>>>(x, Wq, Wk, Wv, Wo, xb, wqb, wkb, wvb, wob);

    dim3 gq(M_TOT / 128, 24);
    gemm_qkv<<<gq, 256, 0, stream>>>(xb, wqb, wkb, wvb, bq, bk, bv, Qb, Kb, Vtb);

    dim3 g2(SEQ / 128, BATCH * N_HEADS);
    attn_kernel<<<g2, 256, 0, stream>>>(Qb, Kb, Vtb, Ao);

    dim3 go(M_TOT / 128, H_SIZE / 64);
    gemm_o<<<go, 256, 0, stream>>>(Ao, wob, bo, x, (float*)d_out);

    ln_kernel<<<M_TOT, 256, 0, stream>>>((float*)d_out, gamma, beta);
}

// Round 7
// 135.333 us; speedup vs baseline: 1.1486x; 1.1486x over previous
//
#include <hip/hip_runtime.h>

#define H_SIZE 1024
#define N_HEADS 16
#define D_K 64
#define SEQ 2048
#define BATCH 2
#define M_TOT 4096  // BATCH*SEQ

typedef __bf16 __attribute__((ext_vector_type(8))) bf16_8;
typedef float __attribute__((ext_vector_type(4))) f32x4;
typedef float __attribute__((ext_vector_type(16))) f32x16;
typedef int __attribute__((ext_vector_type(4))) int4v;

// row-swizzle for 128B-row LDS tiles: spread rows sharing (r&7) across segments
#define SWZ(r) ((((r) & 7) ^ (((r) >> 3) & 7)))

__device__ __forceinline__ ushort f2bf(float f) {
    unsigned int u = __float_as_uint(f);
    unsigned int r = (u + 0x7FFFu + ((u >> 16) & 1u)) >> 16;
    return (ushort)r;
}

__device__ __forceinline__ unsigned int cvtpk(float lo, float hi) {
    unsigned int r;
    asm("v_cvt_pk_bf16_f32 %0, %1, %2" : "=v"(r) : "v"(lo), "v"(hi));
    return r;
}

__device__ __forceinline__ float exp2_raw(float x) {
    float r;
    asm("v_exp_f32 %0, %1" : "=v"(r) : "v"(x));
    return r;
}

__device__ __forceinline__ void gld16(void* lds, const void* g) {
    __builtin_amdgcn_global_load_lds(
        (const __attribute__((address_space(1))) unsigned int*)g,
        (__attribute__((address_space(3))) unsigned int*)lds, 16, 0, 0);
}

// ---------------- fused cast fp32 -> bf16 for x + 4 weight matrices ----------------
__global__ __launch_bounds__(256) void cast_all_kernel(
    const float* __restrict__ x, const float* __restrict__ wq, const float* __restrict__ wk,
    const float* __restrict__ wv, const float* __restrict__ wo,
    ushort* __restrict__ xb, ushort* __restrict__ wqb, ushort* __restrict__ wkb,
    ushort* __restrict__ wvb, ushort* __restrict__ wob) {
    int i = blockIdx.x * 256 + threadIdx.x;  // float4 index
    const float* src;
    ushort* dst;
    int off;
    if (i < 1048576) {          // x: 4096*1024/4
        src = x; dst = xb; off = i;
    } else {
        int j = i - 1048576;    // each W: 1024*1024/4 = 262144
        int w = j >> 18;
        off = j & 262143;
        src = (w == 0) ? wq : (w == 1) ? wk : (w == 2) ? wv : wo;
        dst = (w == 0) ? wqb : (w == 1) ? wkb : (w == 2) ? wvb : wob;
    }
    float4 v = ((const float4*)src)[off];
    ushort4 o;
    o.x = f2bf(v.x); o.y = f2bf(v.y); o.z = f2bf(v.z); o.w = f2bf(v.w);
    ((ushort4*)dst)[off] = o;
}

// ---------------- fused QKV GEMM, gld16-direct 2-phase, BK=64, XOR-swizzled LDS ----------------
// grid (M/128, 24): blockIdx.y>>3 selects {Q,K,V}.
// Staging: linear LDS dest; per-lane GLOBAL source seg pre-swizzled by (srow&7);
// ds_read applies the same XOR -> 2-way conflicts only (free).
__global__ __launch_bounds__(256) void gemm_qkv(
    const ushort* __restrict__ A, const ushort* __restrict__ wq,
    const ushort* __restrict__ wk, const ushort* __restrict__ wv,
    const float* __restrict__ bq, const float* __restrict__ bk, const float* __restrict__ bv,
    ushort* __restrict__ Qb, ushort* __restrict__ Kb, ushort* __restrict__ Vtb) {
    __shared__ ushort As[2][128 * 64];
    __shared__ ushort Bs[2][128 * 64];
    const int tid = threadIdx.x;
    const int lane = tid & 63, wid = tid >> 6;
    const int wr = wid >> 1, wc = wid & 1;
    const int hi = lane >> 4, lo = lane & 15;
    const int bm0 = blockIdx.x * 128;
    const int t3 = blockIdx.y >> 3;
    const int bn0 = (blockIdx.y & 7) * 128;
    const ushort* Bw = (t3 == 0) ? wq : (t3 == 1) ? wk : wv;
    const float* bias = (t3 == 0) ? bq : (t3 == 1) ? bk : bv;

    f32x4 acc[4][4] = {};

    // staging: thread t, chunk c -> LDS row (c*32 + t>>3), seg (t&7) [linear dest];
    // source seg pre-swizzled so LDS slot (r,s) holds global chunk s ^ (r&7)
    const int srow = tid >> 3;
    const int sseg = ((tid & 7) ^ (srow & 7)) * 8;  // ushort offset, swizzled
    const ushort* gaB = A + (size_t)(bm0 + srow) * H_SIZE + sseg;
    const ushort* gbB = Bw + (size_t)(bn0 + srow) * H_SIZE + sseg;
    const int ldsOff = tid * 16;  // bytes

#define STAGE(bb, kt)                                                     \
    {                                                                     \
        char* la = (char*)&As[bb][0] + ldsOff;                            \
        char* lb = (char*)&Bs[bb][0] + ldsOff;                            \
        gld16(la, gaB + (kt));                                            \
        gld16(la + 4096, gaB + 32 * H_SIZE + (kt));                       \
        gld16(la + 8192, gaB + 64 * H_SIZE + (kt));                       \
        gld16(la + 12288, gaB + 96 * H_SIZE + (kt));                      \
        gld16(lb, gbB + (kt));                                            \
        gld16(lb + 4096, gbB + 32 * H_SIZE + (kt));                       \
        gld16(lb + 8192, gbB + 64 * H_SIZE + (kt));                       \
        gld16(lb + 12288, gbB + 96 * H_SIZE + (kt));                      \
    }

    STAGE(0, 0);
    __syncthreads();
    int cur = 0;
    constexpr int NT = H_SIZE / 64;
    const int rsw = lo & 7;  // row&7 for every fragment row (row = base + i*16 + lo)
    for (int t = 0; t < NT; t++) {
        if (t + 1 < NT) STAGE(cur ^ 1, (t + 1) * 64);
#pragma unroll
        for (int kk = 0; kk < 64; kk += 32) {
            bf16_8 af[4], bfv[4];
            const ushort* pa = &As[cur][(wr * 64 + lo) * 64];
            const ushort* pb = &Bs[cur][(wc * 64 + lo) * 64];
            const int sg = (kk >> 3) + hi;  // logical 8-ushort segment index
#pragma unroll
            for (int i = 0; i < 4; i++)
                af[i] = *(const bf16_8*)(pa + i * 16 * 64 + ((sg ^ rsw) * 8));
#pragma unroll
            for (int i = 0; i < 4; i++)
                bfv[i] = *(const bf16_8*)(pb + i * 16 * 64 + ((sg ^ rsw) * 8));
#pragma unroll
            for (int mi = 0; mi < 4; mi++)
#pragma unroll
                for (int ni = 0; ni < 4; ni++)
                    acc[mi][ni] = __builtin_amdgcn_mfma_f32_16x16x32_bf16(
                        af[mi], bfv[ni], acc[mi][ni], 0, 0, 0);
        }
        __syncthreads();
        cur ^= 1;
    }
#undef STAGE

#pragma unroll
    for (int mi = 0; mi < 4; mi++) {
#pragma unroll
        for (int ni = 0; ni < 4; ni++) {
            const int row0 = bm0 + wr * 64 + mi * 16 + hi * 4;
            const int col = bn0 + wc * 64 + ni * 16 + lo;
            const float bv = bias[col];
            const int h = col >> 6, dk = col & 63;
            if (t3 == 2) {
                // V^T [b,h,dk,l]: 4 consecutive l -> one ushort4 (same 8-run, SWZ on dk only)
                const int b = row0 >> 11, l0 = row0 & 2047;
                const int lsw0 = (l0 & ~63) | (((((l0 >> 3) & 7) ^ SWZ(dk)) & 7) << 3) | (l0 & 7);
                ushort4 o;
                o.x = f2bf(acc[mi][ni][0] + bv);
                o.y = f2bf(acc[mi][ni][1] + bv);
                o.z = f2bf(acc[mi][ni][2] + bv);
                o.w = f2bf(acc[mi][ni][3] + bv);
                *(ushort4*)&Vtb[((size_t)(b * N_HEADS + h) * D_K + dk) * SEQ + lsw0] = o;
            } else {
#pragma unroll
                for (int rr = 0; rr < 4; rr++) {
                    const int m = row0 + rr;
                    const int b = m >> 11, l = m & 2047;
                    float val = acc[mi][ni][rr] + bv;
                    if (t3 == 0) {
                        // fold attn scale 1/8 and log2(e) for exp2 softmax
                        Qb[((size_t)(b * N_HEADS + h) * SEQ + l) * D_K + dk] =
                            f2bf(val * 0.18033688f);
                    } else {
                        int dks = ((((dk >> 3) ^ SWZ(l & 63)) & 7) << 3) | (dk & 7);
                        Kb[((size_t)(b * N_HEADS + h) * SEQ + l) * D_K + dks] = f2bf(val);
                    }
                }
            }
        }
    }
}

// ---------------- O-projection GEMM 128x64, gld16-direct 2-phase, XOR-swizzled ----------------
__global__ __launch_bounds__(256) void gemm_o(const ushort* __restrict__ A,
                                              const ushort* __restrict__ Bw,
                                              const float* __restrict__ bias,
                                              const float* __restrict__ resid,
                                              float* __restrict__ outp) {
    __shared__ ushort As[2][128 * 64];
    __shared__ ushort Bs[2][64 * 64];
    const int tid = threadIdx.x;
    const int lane = tid & 63, wid = tid >> 6;
    const int wr = wid >> 1, wc = wid & 1;
    const int hi = lane >> 4, lo = lane & 15;
    const int bm0 = blockIdx.x * 128, bn0 = blockIdx.y * 64;

    f32x4 acc[4][2] = {};

    const int srow = tid >> 3;
    const int sseg = ((tid & 7) ^ (srow & 7)) * 8;
    const ushort* gaB = A + (size_t)(bm0 + srow) * H_SIZE + sseg;
    const ushort* gbB = Bw + (size_t)(bn0 + srow) * H_SIZE + sseg;
    const int ldsOff = tid * 16;

#define STAGE(bb, kt)                                                     \
    {                                                                     \
        char* la = (char*)&As[bb][0] + ldsOff;                            \
        char* lb = (char*)&Bs[bb][0] + ldsOff;                            \
        gld16(la, gaB + (kt));                                            \
        gld16(la + 4096, gaB + 32 * H_SIZE + (kt));                       \
        gld16(la + 8192, gaB + 64 * H_SIZE + (kt));                       \
        gld16(la + 12288, gaB + 96 * H_SIZE + (kt));                      \
        gld16(lb, gbB + (kt));                                            \
        gld16(lb + 4096, gbB + 32 * H_SIZE + (kt));                      \
    }

    STAGE(0, 0);
    __syncthreads();
    int cur = 0;
    constexpr int NT = H_SIZE / 64;
    const int rsw = lo & 7;
    for (int t = 0; t < NT; t++) {
        if (t + 1 < NT) STAGE(cur ^ 1, (t + 1) * 64);
#pragma unroll
        for (int kk = 0; kk < 64; kk += 32) {
            bf16_8 af[4], bfv[2];
            const ushort* pa = &As[cur][(wr * 64 + lo) * 64];
            const ushort* pb = &Bs[cur][(wc * 32 + lo) * 64];
            const int sg = (kk >> 3) + hi;
#pragma unroll
            for (int i = 0; i < 4; i++)
                af[i] = *(const bf16_8*)(pa + i * 16 * 64 + ((sg ^ rsw) * 8));
#pragma unroll
            for (int i = 0; i < 2; i++)
                bfv[i] = *(const bf16_8*)(pb + i * 16 * 64 + ((sg ^ rsw) * 8));
#pragma unroll
            for (int mi = 0; mi < 4; mi++)
#pragma unroll
                for (int ni = 0; ni < 2; ni++)
                    acc[mi][ni] = __builtin_amdgcn_mfma_f32_16x16x32_bf16(
                        af[mi], bfv[ni], acc[mi][ni], 0, 0, 0);
        }
        __syncthreads();
        cur ^= 1;
    }
#undef STAGE

#pragma unroll
    for (int mi = 0; mi < 4; mi++) {
#pragma unroll
        for (int ni = 0; ni < 2; ni++) {
            const int row0 = bm0 + wr * 64 + mi * 16 + hi * 4;
            const int col = bn0 + wc * 32 + ni * 16 + lo;
            const float bv = bias[col];
#pragma unroll
            for (int rr = 0; rr < 4; rr++) {
                const int m = row0 + rr;
                outp[(size_t)m * H_SIZE + col] =
                    acc[mi][ni][rr] + bv + resid[(size_t)m * H_SIZE + col];
            }
        }
    }
}

// ---------------- flash attention, 32x32 MFMA, swapped QK^T, in-register exp2 softmax ----------------
// grid: (SEQ/128, BATCH*N_HEADS), 256 threads = 4 waves x 32 q-rows each.
// Q pre-scaled 0.125*log2e; K [l][dk] and V^T [dk][l] pre-swizzled with SWZ(row).
__global__ __launch_bounds__(256) void attn_kernel(const ushort* __restrict__ Q,
                                                   const ushort* __restrict__ Ksw,
                                                   const ushort* __restrict__ Vsw,
                                                   ushort* __restrict__ Out) {
    __shared__ ushort Ks[2][64 * 64];
    __shared__ ushort Vs[2][64 * 64];
    __shared__ float lsum_lds[4][32];
    const int lane = threadIdx.x & 63, wid = threadIdx.x >> 6;
    const int h32 = lane >> 5, q32 = lane & 31;
    const int bh = blockIdx.y;
    const int q0w = blockIdx.x * 128 + wid * 32;
    const ushort* Qh = Q + (size_t)bh * SEQ * D_K;
    const ushort* Kp = Ksw + (size_t)bh * SEQ * D_K;
    const ushort* Vp = Vsw + (size_t)bh * D_K * SEQ;

    bf16_8 qf[4];
#pragma unroll
    for (int tt = 0; tt < 4; tt++)
        qf[tt] = *(const bf16_8*)(Qh + (size_t)(q0w + q32) * D_K + tt * 16 + h32 * 8);

    f32x16 oacc0 = {}, oacc1 = {};
    float ls = 0.f;

    const int koff = wid * 2048 + lane * 16;
    const int vrow = wid * 16 + (lane >> 3);
    const int vseg = (lane & 7) * 16;

#define STAGE(bb, kt)                                                             \
    {                                                                             \
        const char* kg = (const char*)(Kp + (size_t)(kt) * D_K);                  \
        char* kl = (char*)&Ks[bb][0];                                             \
        gld16(kl + koff, kg + koff);                                              \
        gld16(kl + koff + 1024, kg + koff + 1024);                                \
        char* vl = (char*)&Vs[bb][0];                                             \
        gld16(vl + vrow * 128 + vseg,                                             \
              (const char*)(Vp + (size_t)vrow * SEQ + (kt)) + vseg);              \
        gld16(vl + (vrow + 8) * 128 + vseg,                                       \
              (const char*)(Vp + (size_t)(vrow + 8) * SEQ + (kt)) + vseg);        \
    }

    STAGE(0, 0);
    __syncthreads();
    int buf = 0;
    for (int t = 0; t < SEQ / 64; t++) {
        if (t + 1 < SEQ / 64) STAGE(buf ^ 1, (t + 1) * 64);
        const ushort* kb = &Ks[buf][0];
        const ushort* vb = &Vs[buf][0];
#pragma unroll
        for (int kh = 0; kh < 2; kh++) {
            f32x16 st = {};
            const int krow = kh * 32 + q32;
#pragma unroll
            for (int tt = 0; tt < 4; tt++) {
                int sg = (2 * tt + h32) ^ SWZ(krow);
                bf16_8 kf = *(const bf16_8*)(kb + krow * 64 + sg * 8);
                st = __builtin_amdgcn_mfma_f32_32x32x16_bf16(kf, qf[tt], st, 0, 0, 0);
            }
            float p[16];
#pragma unroll
            for (int rr = 0; rr < 16; rr++) p[rr] = exp2_raw(st[rr]);
            float partial = 0.f;
#pragma unroll
            for (int rr = 0; rr < 16; rr++) partial += p[rr];
            ls += partial + __shfl_xor(partial, 32);

            union { unsigned int w[4]; bf16_8 v; } pf0, pf1;
#pragma unroll
            for (int i = 0; i < 2; i++) {
                unsigned int a = cvtpk(p[2 * i], p[2 * i + 1]);
                unsigned int b = cvtpk(p[4 + 2 * i], p[4 + 2 * i + 1]);
                asm volatile("v_permlane32_swap_b32 %0, %1" : "+v"(a), "+v"(b));
                pf0.w[i] = a; pf0.w[2 + i] = b;
                unsigned int c = cvtpk(p[8 + 2 * i], p[8 + 2 * i + 1]);
                unsigned int d = cvtpk(p[12 + 2 * i], p[12 + 2 * i + 1]);
                asm volatile("v_permlane32_swap_b32 %0, %1" : "+v"(c), "+v"(d));
                pf1.w[i] = c; pf1.w[2 + i] = d;
            }

            {
                const int vr0 = q32;
                int sg0 = (4 * kh + h32) ^ SWZ(vr0);
                int sg1 = (4 * kh + 2 + h32) ^ SWZ(vr0);
                bf16_8 vf0 = *(const bf16_8*)(vb + vr0 * 64 + sg0 * 8);
                bf16_8 vf1 = *(const bf16_8*)(vb + vr0 * 64 + sg1 * 8);
                oacc0 = __builtin_amdgcn_mfma_f32_32x32x16_bf16(pf0.v, vf0, oacc0, 0, 0, 0);
                oacc0 = __builtin_amdgcn_mfma_f32_32x32x16_bf16(pf1.v, vf1, oacc0, 0, 0, 0);
            }
            {
                const int vr1 = 32 + q32;
                int sg0 = (4 * kh + h32) ^ SWZ(vr1);
                int sg1 = (4 * kh + 2 + h32) ^ SWZ(vr1);
                bf16_8 vf0 = *(const bf16_8*)(vb + vr1 * 64 + sg0 * 8);
                bf16_8 vf1 = *(const bf16_8*)(vb + vr1 * 64 + sg1 * 8);
                oacc1 = __builtin_amdgcn_mfma_f32_32x32x16_bf16(pf0.v, vf0, oacc1, 0, 0, 0);
                oacc1 = __builtin_amdgcn_mfma_f32_32x32x16_bf16(pf1.v, vf1, oacc1, 0, 0, 0);
            }
        }
        __syncthreads();
        buf ^= 1;
    }
#undef STAGE

    if (lane < 32) lsum_lds[wid][q32] = 1.0f / ls;
    const int b = bh >> 4, h = bh & 15;
#pragma unroll
    for (int rr = 0; rr < 16; rr++) {
        const int qloc = (rr & 3) + 8 * (rr >> 2) + 4 * h32;
        const float inv = lsum_lds[wid][qloc];
        const int l = q0w + qloc;
        ushort* orow = Out + ((size_t)(b * SEQ + l)) * H_SIZE + h * 64;
        orow[q32] = f2bf(oacc0[rr] * inv);
        orow[32 + q32] = f2bf(oacc1[rr] * inv);
    }
}

// ---------------- LayerNorm in-place on d_out ----------------
__global__ __launch_bounds__(256) void ln_kernel(float* __restrict__ y,
                                                 const float* __restrict__ gamma,
                                                 const float* __restrict__ beta) {
    const int row = blockIdx.x;
    float4* p = (float4*)(y + (size_t)row * H_SIZE);
    float4 v = p[threadIdx.x];
    float s = v.x + v.y + v.z + v.w;
    float s2 = v.x * v.x + v.y * v.y + v.z * v.z + v.w * v.w;
#pragma unroll
    for (int off = 1; off < 64; off <<= 1) {
        s += __shfl_xor(s, off);
        s2 += __shfl_xor(s2, off);
    }
    __shared__ float ss[4], ss2[4];
    const int wid = threadIdx.x >> 6, lane = threadIdx.x & 63;
    if (lane == 0) { ss[wid] = s; ss2[wid] = s2; }
    __syncthreads();
    s = ss[0] + ss[1] + ss[2] + ss[3];
    s2 = ss2[0] + ss2[1] + ss2[2] + ss2[3];
    const float mean = s * (1.0f / H_SIZE);
    const float var = s2 * (1.0f / H_SIZE) - mean * mean;
    const float rstd = rsqrtf(var + 1e-5f);
    const float4 g = ((const float4*)gamma)[threadIdx.x];
    const float4 bt = ((const float4*)beta)[threadIdx.x];
    float4 o;
    o.x = (v.x - mean) * rstd * g.x + bt.x;
    o.y = (v.y - mean) * rstd * g.y + bt.y;
    o.z = (v.z - mean) * rstd * g.z + bt.z;
    o.w = (v.w - mean) * rstd * g.w + bt.w;
    p[threadIdx.x] = o;
}

extern "C" void kernel_launch(void* const* d_in, const int* in_sizes, int n_in,
                              void* d_out, int out_size, void* d_ws, size_t ws_size,
                              hipStream_t stream) {
    const float* x = (const float*)d_in[0];
    const float* Wq = (const float*)d_in[1];
    const float* bq = (const float*)d_in[2];
    const float* Wk = (const float*)d_in[3];
    const float* bk = (const float*)d_in[4];
    const float* Wv = (const float*)d_in[5];
    const float* bv = (const float*)d_in[6];
    const float* Wo = (const float*)d_in[7];
    const float* bo = (const float*)d_in[8];
    const float* gamma = (const float*)d_in[9];
    const float* beta = (const float*)d_in[10];

    char* ws = (char*)d_ws;
    ushort* xb  = (ushort*)(ws);                    // 8 MB: x bf16 [4096,1024]
    ushort* wqb = (ushort*)(ws + (8u << 20));       // 2 MB each
    ushort* wkb = (ushort*)(ws + (10u << 20));
    ushort* wvb = (ushort*)(ws + (12u << 20));
    ushort* wob = (ushort*)(ws + (14u << 20));
    ushort* Qb  = (ushort*)(ws + (16u << 20));      // 8 MB [b,h,l,dk] (x 0.125*log2e)
    ushort* Kb  = (ushort*)(ws + (24u << 20));      // 8 MB [b,h,l,dk] SWZ-swizzled
    ushort* Vtb = (ushort*)(ws + (32u << 20));      // 8 MB [b,h,dk,l] SWZ-swizzled
    ushort* Ao  = (ushort*)(ws + (40u << 20));      // 8 MB attn out bf16 [m,H]

    cast_all_kernel<<<8192, 256, 0, stream>>>(x, Wq, Wk, Wv, Wo, xb, wqb, wkb, wvb, wob);

    dim3 gq(M_TOT / 128, 24);
    gemm_qkv<<<gq, 256, 0, stream>>>(xb, wqb, wkb, wvb, bq, bk, bv, Qb, Kb, Vtb);

    dim3 g2(SEQ / 128, BATCH * N_HEADS);
    attn_kernel<<<g2, 256, 0, stream>>>(Qb, Kb, Vtb, Ao);

    dim3 go(M_TOT / 128, H_SIZE / 64);
    gemm_o<<<go, 256, 0, stream>>>(Ao, wob, bo, x, (float*)d_out);

    ln_kernel<<<M_TOT, 256, 0, stream>>>((float*)d_out, gamma, beta);
}